// Round 13
// baseline (703.225 us; speedup 1.0000x reference)
//
#include <hip/hip_runtime.h>

#define N_ 2000
#define L_ 1024

__device__ __forceinline__ float rcpf(float d) { return __builtin_amdgcn_rcpf(d); }
__device__ __forceinline__ float ex2(float x)  { return __builtin_amdgcn_exp2f(x); }

// R12 math (passed, absmax 0.0156), launched as 32 blocks x 512 threads:
// a workgroup's 8 waves all land on ONE CU, round-robin over its 4 SIMDs ->
// 2 co-resident waves per SIMD. Lone-wave issue cadence measured ~4.3 cy/inst
// (R6-R12 invariant); co-residency lets the SIMD interleave two instruction
// streams toward the 2.0-2.2 cy/inst hardware rate.
// PRE: 0 = prefetch z[K+7] (no clamp, K+7<=1991), 1 = clamped prefetch, 2 = none.
#define STEP1(K, RS, PRE)                                                     \
  {                                                                           \
    const int kk = (K);                                                       \
    float zc = zb[RS];                                                        \
    if ((PRE) == 0) {                                                         \
      zb[RS] = (zrow + (kk + 7) * L_)[lu];                                    \
    } else if ((PRE) == 1) {                                                  \
      int kc = kk + 7; kc = kc < 1998 ? kc : 1998;                            \
      zb[RS] = (zrow + kc * L_)[lu];                                          \
    }                                                                         \
    /* conductances; G1 = 1+G, tVD = 0.02E + 2V + 0.02 pre-folded */          \
    float mh   = m * h;                                                       \
    float m2   = m * m;                                                       \
    float valm = m2 * mh;              /* m^3 h */                            \
    float n2   = n * n;                                                       \
    float valn = n2 * n2;              /* n^4  */                             \
    float G1   = __fmaf_rn(valm, 0.4f,                                        \
                 __fmaf_rn(valn, 0.35f, __fmaf_rn(y, 0.01f, 1.003f)));        \
    float tVD  = __fmaf_rn(valm, 44.0f,                                       \
                 __fmaf_rn(valn, -53.9f, __fmaf_rn(V, 2.0f, -0.37f)));        \
    float rV   = rcpf(G1);                                                    \
    float Vn   = __fmaf_rn(tVD, rV, -V);   /* (V(1-G)+.02(E+1))/(1+G) */      \
    /* m,n rates: one ex2 from Vn */                                          \
    float eRm  = ex2(__fmaf_rn(Vn, K9, 35.0f * K9));   /* e^{(Vn+35)/9} */    \
    float dm   = eRm - 1.0f;                                                  \
    float dn   = __fmaf_rn(CN, eRm, -1.0f);            /* eRn - 1 */          \
    float um   = Vn + 35.0f;                                                  \
    float un   = Vn - 25.0f;                                                  \
    float rrm  = rcpf(dm);                                                    \
    float rrn  = rcpf(dn);                                                    \
    float urm  = um * rrm;                                                    \
    float urn  = un * rrn;                                                    \
    bool patm  = (Vn == -35.0f);                                              \
    bool patn  = (Vn == 25.0f);                                               \
    urm = patm ? 9.0f : urm;           /* limit; tm=9, tn=TNPAT exactly */    \
    urn = patn ? 9.0f : urn;                                                  \
    float sm   = urm * __fmaf_rn(0.00182f, eRm, 0.00124f);                    \
    float sn   = urn * __fmaf_rn(KXN, eRm, 0.00002f);                         \
    float tm   = urm * eRm;                                                   \
    float tn   = urn * eRm;                                                   \
    /* H (0.01 folded): A=0.01*aH, B=0.01*bH */                               \
    float A    = ex2(__fmaf_rn(Vn, -K12, CAH));                               \
    float Bv   = ex2(__fmaf_rn(Vn,  K12, CBH));                               \
    float sh   = A + Bv;                                                      \
    float sy   = __fmaf_rn(zc, 0.01f, 0.001f);                                \
    /* numerators: coef*t = DT*a-rate */                                      \
    float numm = __fmaf_rn(tm, 0.00364f, __fmaf_rn(-sm, m, m));               \
    float numn = __fmaf_rn(tn, KAN,      __fmaf_rn(-sn, n, n));               \
    float numh = __fmaf_rn(A,  2.0f,     __fmaf_rn(-sh, h, h));               \
    float numy = __fmaf_rn(zc, 0.02f,    __fmaf_rn(-sy, y, y));               \
    m = numm * rcpf(1.0f + sm);                                               \
    n = numn * rcpf(1.0f + sn);                                               \
    h = numh * rcpf(1.0f + sh);                                               \
    y = numy * (1.0f - sy);            /* 1/(1+sy) ~ 1-sy, sy<=0.011 */       \
    V = Vn;                                                                   \
    /* sigmoid((Vn+20)/3) = 1/(1+e^{-(Vn+20)/3}) */                           \
    float sg = rcpf(1.0f + ex2(__fmaf_rn(Vn, -K3, -20.0f * K3)));             \
    (orow + kk * L_)[lu] = sg;                                                \
  }

__global__ __launch_bounds__(512) void hh_kernel(const float* __restrict__ z,
                                                 float* __restrict__ out) {
    const int t  = blockIdx.x * 512 + threadIdx.x;         // 0 .. 16383
    const int bu = __builtin_amdgcn_readfirstlane(t >> 10); // wave-uniform batch
    const int lu = t & 1023;                                // lane column

    const float* zrow = z   + (size_t)bu * (N_ * L_);
    float*       orow = out + (size_t)bu * (N_ * L_);

    const float K9  = 0.16029944898766259f;    // log2(e)/9
    const float K12 = 0.12022458674074695f;    // log2(e)/12
    const float K3  = 0.48089834696298783f;    // log2(e)/3
    const float CN  = 0.0012726338013398079f;  // e^{-60/9}: eRn = CN*eRm
    const float KXN = 2.5452676026796158e-7f;  // 0.0002*CN
    const float KAN = 5.0905352053592316e-7f;  // 0.0004*CN (numn coef)
    const float CAH = -19.46406899644195f;     // -90*K12 + log2(0.0025)
    const float CBH = -4.556220240589328f;     //  34*K12 + log2(0.0025)

    float V = -70.0f;
    float m = 0.0f, n = 0.0f, h = 1.0f, y = 0.0f;

    float zb[8];
#pragma unroll
    for (int i = 0; i < 8; ++i) zb[i] = (zrow + i * L_)[lu];

    // row 0: sigmoid((-70+20)/3), constant
    orow[lu] = 5.777750e-8f;

    int k = 1;
    for (int g = 0; g < 248; ++g) {            // K = 1 .. 1984, clamp-free
#pragma unroll
        for (int j = 0; j < 8; ++j) {
            STEP1(k + j, j, 0)
        }
        k += 8;
    }
#pragma unroll
    for (int j = 0; j < 8; ++j) {              // K = 1985 .. 1992, clamped
        STEP1(1985 + j, j, 1)
    }
#pragma unroll
    for (int j = 0; j < 7; ++j) {              // K = 1993 .. 1999, no prefetch
        STEP1(1993 + j, j, 2)
    }
}

extern "C" void kernel_launch(void* const* d_in, const int* in_sizes, int n_in,
                              void* d_out, int out_size, void* d_ws, size_t ws_size,
                              hipStream_t stream) {
    const float* z = (const float*)d_in[0];
    float* out = (float*)d_out;
    // 16384 chains = 32 blocks x 512 threads: 8 waves/CU = 2 waves/SIMD
    // (a workgroup's waves round-robin over the 4 SIMDs of ONE CU).
    hh_kernel<<<32, 512, 0, stream>>>(z, out);
}

// Round 14
// 478.110 us; speedup vs baseline: 1.4708x; 1.4708x over previous
//
#include <hip/hip_runtime.h>

#define N_ 2000
#define L_ 1024

__device__ __forceinline__ float rcpf(float d) { return __builtin_amdgcn_rcpf(d); }
__device__ __forceinline__ float ex2(float x)  { return __builtin_amdgcn_exp2f(x); }

// R8 (session best: 331 us dispatch / 478.9 us bench, absmax 0.0039).
// Issue-diet step, ~66 VALU slots: separate rcp per gate (slot-optimal),
// eRn/aM/aN folded into constants, H exps carry 0.01*0.25 in the exp2
// constant, SALU addressing via wave-uniform row bases.
// Measured floor: wall ~397 cy/step = ~300 cy VALU occupancy + ~100 cy
// exposed dependent latency (lone wave/SIMD; 256 waves fixed by problem).
// PRE: 0 = prefetch z[K+7] (no clamp, K+7<=1991), 1 = clamped prefetch, 2 = none.
#define STEP1(K, RS, PRE)                                                     \
  {                                                                           \
    const int kk = (K);                                                       \
    float zc = zb[RS];                                                        \
    if ((PRE) == 0) {                                                         \
      zb[RS] = (zrow + (kk + 7) * L_)[lu];                                    \
    } else if ((PRE) == 1) {                                                  \
      int kc = kk + 7; kc = kc < 1998 ? kc : 1998;                            \
      zb[RS] = (zrow + kc * L_)[lu];                                          \
    }                                                                         \
    /* conductances */                                                        \
    float mh   = m * h;                                                       \
    float m2   = m * m;                                                       \
    float valm = m2 * mh;              /* m^3 h */                            \
    float n2   = n * n;                                                       \
    float valn = n2 * n2;              /* n^4  */                             \
    float gy   = __fmaf_rn(y, 0.01f, 0.003f);                                 \
    float G    = __fmaf_rn(valm, 0.4f, __fmaf_rn(valn, 0.35f, gy));           \
    float E    = __fmaf_rn(valm, 2200.0f, __fmaf_rn(valn, -2695.0f, -19.5f)); \
    float rV   = rcpf(1.0f + G);                                              \
    float tVD  = __fmaf_rn(E, 0.02f, __fmaf_rn(2.0f, V, 0.02f));              \
    float Vn   = __fmaf_rn(tVD, rV, -V);   /* (V(1-G)+.02(E+1))/(1+G) */      \
    /* m,n rates: one ex2; eRn = CN*eRm folded into coefficients */           \
    float eRm  = ex2(__fmaf_rn(Vn, K9, 35.0f * K9));   /* e^{(Vn+35)/9} */    \
    float dm   = eRm - 1.0f;                                                  \
    float dn   = __fmaf_rn(CN, eRm, -1.0f);            /* eRn - 1 */          \
    float um   = Vn + 35.0f;                                                  \
    float un   = Vn - 25.0f;                                                  \
    float rrm  = rcpf(dm);                                                    \
    float rrn  = rcpf(dn);                                                    \
    float urm  = um * rrm;                                                    \
    float urn  = un * rrn;                                                    \
    float sm   = urm * __fmaf_rn(0.00182f, eRm, 0.00124f);                    \
    float sn   = urn * __fmaf_rn(KXN, eRm, 0.00002f);                         \
    float tm   = urm * eRm;                                                   \
    float tn   = urn * eRm;                                                   \
    bool patm  = (Vn == -35.0f);                                              \
    bool patn  = (Vn == 25.0f);                                               \
    sm = patm ? 0.02798f : sm;   tm = patm ? 9.0f   : tm;                     \
    sn = patn ? 0.0026f  : sn;   tn = patn ? TNPAT  : tn;                     \
    /* H (0.01 folded): A=0.01*aH, B=0.01*bH */                               \
    float A    = ex2(__fmaf_rn(Vn, -K12, CAH));                               \
    float Bv   = ex2(__fmaf_rn(Vn,  K12, CBH));                               \
    float sh   = A + Bv;                                                      \
    float sy   = __fmaf_rn(zc, 0.01f, 0.001f);                                \
    /* numerators: coef*t = DT*a-rate */                                      \
    float numm = __fmaf_rn(tm, 0.00364f, __fmaf_rn(-sm, m, m));               \
    float numn = __fmaf_rn(tn, KAN,      __fmaf_rn(-sn, n, n));               \
    float numh = __fmaf_rn(A,  2.0f,     __fmaf_rn(-sh, h, h));               \
    float numy = __fmaf_rn(zc, 0.02f,    __fmaf_rn(-sy, y, y));               \
    m = numm * rcpf(1.0f + sm);                                               \
    n = numn * rcpf(1.0f + sn);                                               \
    h = numh * rcpf(1.0f + sh);                                               \
    y = numy * rcpf(1.0f + sy);                                               \
    V = Vn;                                                                   \
    /* sigmoid((Vn+20)/3): ts = eRm^3 e^-5 */                                 \
    float e2 = eRm * eRm;                                                     \
    float ts = (e2 * eRm) * 0.006737946999085467f;                            \
    float sg = ts * rcpf(1.0f + ts);                                          \
    (orow + kk * L_)[lu] = sg;                                                \
  }

__global__ __launch_bounds__(64) void hh_kernel(const float* __restrict__ z,
                                                float* __restrict__ out) {
    const int t  = blockIdx.x * 64 + threadIdx.x;          // 0 .. 16383
    const int bu = __builtin_amdgcn_readfirstlane(t >> 10); // wave-uniform batch
    const int lu = t & 1023;                                // lane column

    const float* zrow = z   + (size_t)bu * (N_ * L_);
    float*       orow = out + (size_t)bu * (N_ * L_);

    const float K9  = 0.16029944898766259f;    // log2(e)/9
    const float K12 = 0.12022458674074695f;    // log2(e)/12
    const float CN  = 0.0012726338013398079f;  // e^{-60/9}: eRn = CN*eRm
    const float KXN = 2.5452676026796158e-7f;  // 0.0002*CN
    const float KAN = 5.0905352053592316e-7f;  // 0.0004*CN (numn coef)
    const float TNPAT = 7071.948f;             // 0.0036/KAN (patched tn)
    const float CAH = -19.46406899644195f;     // -90*K12 + log2(0.0025)
    const float CBH = -4.556220240589328f;     //  34*K12 + log2(0.0025)

    float V = -70.0f;
    float m = 0.0f, n = 0.0f, h = 1.0f, y = 0.0f;

    float zb[8];
#pragma unroll
    for (int i = 0; i < 8; ++i) zb[i] = (zrow + i * L_)[lu];

    // row 0: sigmoid((-70+20)/3), constant
    orow[lu] = 5.777750e-8f;

    int k = 1;
    for (int g = 0; g < 248; ++g) {            // K = 1 .. 1984, clamp-free
#pragma unroll
        for (int j = 0; j < 8; ++j) {
            STEP1(k + j, j, 0)
        }
        k += 8;
    }
#pragma unroll
    for (int j = 0; j < 8; ++j) {              // K = 1985 .. 1992, clamped
        STEP1(1985 + j, j, 1)
    }
#pragma unroll
    for (int j = 0; j < 7; ++j) {              // K = 1993 .. 1999, no prefetch
        STEP1(1993 + j, j, 2)
    }
}

extern "C" void kernel_launch(void* const* d_in, const int* in_sizes, int n_in,
                              void* d_out, int out_size, void* d_ws, size_t ws_size,
                              hipStream_t stream) {
    const float* z = (const float*)d_in[0];
    float* out = (float*)d_out;
    // 16384 chains x 1 lane = 16384 threads = 256 waves (1 per CU)
    hh_kernel<<<256, 64, 0, stream>>>(z, out);
}